// Round 1
// baseline (193.729 us; speedup 1.0000x reference)
//
#include <hip/hip_runtime.h>

// ConvDistanceTransform closed form:
//   D = Chebyshev distance transform of seeds (exact, separable)
//   i = (D-1)/3 ; out = 3.5*i - 0.35*log( sum_{q in 7x7, D(q)<=3i} exp(-|p-q|_2/0.35) )
// Matches the reference's iterative conv/mask/boundary logic exactly (integer-exact
// structure; value differs only by fp summation order).

#define BIGV (1 << 20)

// ---------- Phase 1: per-row 1D distance (min-plus scan), store uint8 (sat 255) ----
__global__ __launch_bounds__(256) void k_rowdist(const float* __restrict__ img,
                                                 unsigned char* __restrict__ d1) {
  const int row = blockIdx.x;          // 0 .. nch*256-1
  const int x = threadIdx.x;           // 0..255
  const int lane = x & 63;
  const int wave = x >> 6;
  __shared__ float vrow[256];
  __shared__ int wtotA[4];
  __shared__ int wtotB[4];
  __shared__ int dbs[256];

  const float v = img[(size_t)row * 256 + x];
  vrow[x] = v;

  // forward: df[x] = x + inclusive-prefix-min over x'<=x of (seed ? -x' : BIG)
  int a = (v != 0.0f) ? -x : BIGV;
#pragma unroll
  for (int off = 1; off < 64; off <<= 1) {
    int o = __shfl_up(a, off, 64);
    if (lane >= off) a = min(a, o);
  }
  if (lane == 63) wtotA[wave] = a;
  __syncthreads();
#pragma unroll
  for (int w = 0; w < 3; ++w)
    if (w < wave) a = min(a, wtotA[w]);
  const int df = x + a;

  // backward: thread handles element xr = 255-x; prefix over thread order = suffix
  const int xr = 255 - x;
  const float vr = vrow[xr];
  int b = (vr != 0.0f) ? xr : BIGV;
#pragma unroll
  for (int off = 1; off < 64; off <<= 1) {
    int o = __shfl_up(b, off, 64);
    if (lane >= off) b = min(b, o);
  }
  if (lane == 63) wtotB[wave] = b;
  __syncthreads();
#pragma unroll
  for (int w = 0; w < 3; ++w)
    if (w < wave) b = min(b, wtotB[w]);
  dbs[xr] = b - xr;
  __syncthreads();

  int d = min(df, dbs[x]);
  d = min(d, 255);
  d1[(size_t)row * 256 + x] = (unsigned char)d;
}

// ---------- Phase 2: D(y,x) = min_y' max(|y-y'|, d1(y',x)); in-place per 64-col tile --
__global__ __launch_bounds__(256) void k_coldist(unsigned char* dbuf) {
  const int ch = blockIdx.y;   // channel
  const int xt = blockIdx.x;   // 0..3
  const int x0 = xt * 64;
  __shared__ __align__(16) unsigned char s[256 * 64];  // [y][xl], 16 KiB
  const size_t base = (size_t)ch * 65536 + x0;

  // load 64B per row (4 x uint4), rows 0..255 -> 1024 chunks
  for (int idx = threadIdx.x; idx < 1024; idx += 256) {
    const int y = idx >> 2, seg = idx & 3;
    *reinterpret_cast<uint4*>(&s[y * 64 + seg * 16]) =
        *reinterpret_cast<const uint4*>(&dbuf[base + (size_t)y * 256 + seg * 16]);
  }
  __syncthreads();

  for (int p = threadIdx.x; p < 16384; p += 256) {
    const int y = p >> 6, xl = p & 63;
    int best = s[y * 64 + xl];          // k=0 candidate: max(0, d1) = d1
    for (int k = 1; k < best; ++k) {    // candidates with |dy|=k cost >= k
      const int yu = y - k, yd = y + k;
      if (yu >= 0) {
        int c = s[yu * 64 + xl];
        c = max(k, c);
        best = min(best, c);
      }
      if (yd < 256) {
        int c = s[yd * 64 + xl];
        c = max(k, c);
        best = min(best, c);
      }
    }
    dbuf[base + (size_t)y * 256 + xl] = (unsigned char)best;
  }
}

// ---------- Phase 3: fused thresholded 7x7 log-sum-exp epilogue ----------------------
__global__ __launch_bounds__(256) void k_final(const unsigned char* __restrict__ Dbuf,
                                               float* __restrict__ out) {
  const int ch = blockIdx.z;
  const int tx = blockIdx.x, ty = blockIdx.y;
  const int lx = threadIdx.x, ly = threadIdx.y;
  const int tid = lx + ly * 16;

  __shared__ float wk[49];
  __shared__ unsigned char Ds[22 * 22];

  if (tid < 49) {
    const int dy = tid / 7 - 3, dx = tid % 7 - 3;
    wk[tid] = expf(sqrtf((float)(dx * dx + dy * dy)) / -0.35f);
  }

  const int gy0 = ty * 16 - 3, gx0 = tx * 16 - 3;
  const size_t cbase = (size_t)ch * 65536;
  for (int idx = tid; idx < 484; idx += 256) {
    const int r = idx / 22, c = idx % 22;
    const int gy = gy0 + r, gx = gx0 + c;
    unsigned char v = 255;  // outside image: never <= T (T<=252) -> contributes 0
    if (gy >= 0 && gy < 256 && gx >= 0 && gx < 256)
      v = Dbuf[cbase + (size_t)gy * 256 + gx];
    Ds[idx] = v;
  }
  __syncthreads();

  const int D0 = Ds[(ly + 3) * 22 + (lx + 3)];
  float res = 0.0f;
  if (D0 > 0) {
    const int ii = (D0 - 1) / 3;  // iteration index at which this pixel is written
    const int T = 3 * ii;         // boundary_i = { D <= T }
    float conv = 0.0f;
#pragma unroll
    for (int dy = 0; dy < 7; ++dy)
#pragma unroll
      for (int dx = 0; dx < 7; ++dx) {
        const int q = Ds[(ly + dy) * 22 + (lx + dx)];
        if (q <= T) conv += wk[dy * 7 + dx];
      }
    if (conv > 0.0f) res = (float)ii * 3.5f - 0.35f * logf(conv);
  }
  out[cbase + (size_t)(ty * 16 + ly) * 256 + (tx * 16 + lx)] = res;
}

extern "C" void kernel_launch(void* const* d_in, const int* in_sizes, int n_in,
                              void* d_out, int out_size, void* d_ws, size_t ws_size,
                              hipStream_t stream) {
  const float* img = (const float*)d_in[0];
  float* out = (float*)d_out;
  unsigned char* Dbuf = (unsigned char*)d_ws;

  const int total = in_sizes[0];     // B*C*H*W
  const int nch = total >> 16;       // B*C (H=W=256)

  k_rowdist<<<dim3(nch * 256), dim3(256), 0, stream>>>(img, Dbuf);
  k_coldist<<<dim3(4, nch), dim3(256), 0, stream>>>(Dbuf);
  k_final<<<dim3(16, 16, nch), dim3(16, 16), 0, stream>>>(Dbuf, out);
}

// Round 2
// 69.967 us; speedup vs baseline: 2.7688x; 2.7688x over previous
//
#include <hip/hip_runtime.h>

// ConvDistanceTransform closed form:
//   D = Chebyshev distance transform of seeds (exact, separable)
//   i = (D-1)/3 ; out = 3.5*i - 0.35*log( sum_{q in 7x7, D(q)<=3i} exp(-|p-q|_2/0.35) )

#define BIGV (1 << 20)

// ---------- Phase 1: per-row 1D distance, wave-per-row, register scans ----------
__global__ __launch_bounds__(256) void k_rowdist(const float* __restrict__ img,
                                                 unsigned char* __restrict__ d1) {
  const int lane = threadIdx.x & 63;
  const int wv = threadIdx.x >> 6;
  const int row = blockIdx.x * 4 + wv;
  const int x0 = lane * 4;

  const float4 v = *reinterpret_cast<const float4*>(&img[(size_t)row * 256 + x0]);

  // forward: df[x] = x + min_{x'<=x} (seed(x') ? -x' : BIG)
  int c0 = (v.x != 0.0f) ? -x0 : BIGV;
  int c1 = (v.y != 0.0f) ? -(x0 + 1) : BIGV;
  int c2 = (v.z != 0.0f) ? -(x0 + 2) : BIGV;
  int c3 = (v.w != 0.0f) ? -(x0 + 3) : BIGV;
  const int p0 = c0;
  const int p1 = min(c1, p0);
  const int p2 = min(c2, p1);
  const int p3 = min(c3, p2);
  int incl = p3;
#pragma unroll
  for (int off = 1; off < 64; off <<= 1) {
    int o = __shfl_up(incl, off, 64);
    if (lane >= off) incl = min(incl, o);
  }
  int excl = __shfl_up(incl, 1, 64);
  if (lane == 0) excl = BIGV;
  const int df0 = x0 + min(p0, excl);
  const int df1 = x0 + 1 + min(p1, excl);
  const int df2 = x0 + 2 + min(p2, excl);
  const int df3 = x0 + 3 + min(p3, excl);

  // backward: db[x] = min_{x'>=x} (seed(x') ? x' : BIG) - x
  int g0 = (v.x != 0.0f) ? x0 : BIGV;
  int g1 = (v.y != 0.0f) ? (x0 + 1) : BIGV;
  int g2 = (v.z != 0.0f) ? (x0 + 2) : BIGV;
  int g3 = (v.w != 0.0f) ? (x0 + 3) : BIGV;
  const int q3 = g3;
  const int q2 = min(g2, q3);
  const int q1 = min(g1, q2);
  const int q0 = min(g0, q1);
  int incl2 = q0;
#pragma unroll
  for (int off = 1; off < 64; off <<= 1) {
    int o = __shfl_down(incl2, off, 64);
    if (lane < 64 - off) incl2 = min(incl2, o);
  }
  int excl2 = __shfl_down(incl2, 1, 64);
  if (lane == 63) excl2 = BIGV;
  const int db0 = min(q0, excl2) - x0;
  const int db1 = min(q1, excl2) - (x0 + 1);
  const int db2 = min(q2, excl2) - (x0 + 2);
  const int db3 = min(q3, excl2) - (x0 + 3);

  const unsigned int d0 = (unsigned int)min(min(df0, db0), 255);
  const unsigned int d1v = (unsigned int)min(min(df1, db1), 255);
  const unsigned int d2 = (unsigned int)min(min(df2, db2), 255);
  const unsigned int d3 = (unsigned int)min(min(df3, db3), 255);
  *reinterpret_cast<unsigned int*>(&d1[(size_t)row * 256 + x0]) =
      d0 | (d1v << 8) | (d2 << 16) | (d3 << 24);
}

// ---------- Phase 2: D(y,x) = min_y' max(|y-y'|, d1(y',x)); 16-col strips, in-place --
__global__ __launch_bounds__(256) void k_coldist(unsigned char* dbuf) {
  const int ch = blockIdx.y;
  const int xt = blockIdx.x;  // 0..15
  const int x0 = xt * 16;
  __shared__ __align__(16) unsigned char s[256][16];  // 4 KiB
  const size_t base = (size_t)ch * 65536 + x0;

  {
    const int y = threadIdx.x;
    *reinterpret_cast<uint4*>(&s[y][0]) =
        *reinterpret_cast<const uint4*>(&dbuf[base + (size_t)y * 256]);
  }
  __syncthreads();

#pragma unroll
  for (int it = 0; it < 4; ++it) {
    const int item = threadIdx.x + it * 256;  // 0..1023
    const int y = item >> 2, xg = item & 3;
    const unsigned int c = *reinterpret_cast<const unsigned int*>(&s[y][xg * 4]);
    int b0 = c & 255, b1 = (c >> 8) & 255, b2 = (c >> 16) & 255, b3 = c >> 24;
    int bm = max(max(b0, b1), max(b2, b3));
    for (int k = 1; k < bm; ++k) {
      // clamped rows give over-estimates of valid candidates -> still exact
      const int yu = max(y - k, 0), yd = min(y + k, 255);
      const unsigned int u = *reinterpret_cast<const unsigned int*>(&s[yu][xg * 4]);
      const unsigned int w = *reinterpret_cast<const unsigned int*>(&s[yd][xg * 4]);
      b0 = min(b0, max(k, (int)(u & 255)));
      b1 = min(b1, max(k, (int)((u >> 8) & 255)));
      b2 = min(b2, max(k, (int)((u >> 16) & 255)));
      b3 = min(b3, max(k, (int)(u >> 24)));
      b0 = min(b0, max(k, (int)(w & 255)));
      b1 = min(b1, max(k, (int)((w >> 8) & 255)));
      b2 = min(b2, max(k, (int)((w >> 16) & 255)));
      b3 = min(b3, max(k, (int)(w >> 24)));
      bm = max(max(b0, b1), max(b2, b3));
    }
    *reinterpret_cast<unsigned int*>(&dbuf[base + (size_t)y * 256 + xg * 4]) =
        (unsigned int)b0 | ((unsigned int)b1 << 8) | ((unsigned int)b2 << 16) |
        ((unsigned int)b3 << 24);
  }
}

// ---------- Phase 3: fused thresholded 7x7 log-sum-exp epilogue ----------------------
__global__ __launch_bounds__(256) void k_final(const unsigned char* __restrict__ Dbuf,
                                               float* __restrict__ out) {
  const int ch = blockIdx.z;
  const int tx = blockIdx.x, ty = blockIdx.y;
  const int lx = threadIdx.x, ly = threadIdx.y;
  const int tid = lx + ly * 16;

  __shared__ float wk[49];
  __shared__ unsigned char Ds[22 * 22];

  if (tid < 49) {
    const int dy = tid / 7 - 3, dx = tid % 7 - 3;
    wk[tid] = expf(sqrtf((float)(dx * dx + dy * dy)) / -0.35f);
  }

  const int gy0 = ty * 16 - 3, gx0 = tx * 16 - 3;
  const size_t cbase = (size_t)ch * 65536;
  for (int idx = tid; idx < 484; idx += 256) {
    const int r = idx / 22, c = idx % 22;
    const int gy = gy0 + r, gx = gx0 + c;
    unsigned char v = 255;  // outside image: never <= T -> contributes 0
    if (gy >= 0 && gy < 256 && gx >= 0 && gx < 256)
      v = Dbuf[cbase + (size_t)gy * 256 + gx];
    Ds[idx] = v;
  }
  __syncthreads();

  const int D0 = Ds[(ly + 3) * 22 + (lx + 3)];
  float res = 0.0f;
  if (D0 > 0) {
    const int ii = (D0 - 1) / 3;
    const int T = 3 * ii;
    float conv = 0.0f;
#pragma unroll
    for (int dy = 0; dy < 7; ++dy)
#pragma unroll
      for (int dx = 0; dx < 7; ++dx) {
        const int q = Ds[(ly + dy) * 22 + (lx + dx)];
        if (q <= T) conv += wk[dy * 7 + dx];
      }
    if (conv > 0.0f) res = (float)ii * 3.5f - 0.35f * logf(conv);
  }
  out[cbase + (size_t)(ty * 16 + ly) * 256 + (tx * 16 + lx)] = res;
}

extern "C" void kernel_launch(void* const* d_in, const int* in_sizes, int n_in,
                              void* d_out, int out_size, void* d_ws, size_t ws_size,
                              hipStream_t stream) {
  const float* img = (const float*)d_in[0];
  float* out = (float*)d_out;
  unsigned char* Dbuf = (unsigned char*)d_ws;

  const int total = in_sizes[0];  // B*C*H*W
  const int nch = total >> 16;    // B*C (H=W=256)

  k_rowdist<<<dim3(nch * 64), dim3(256), 0, stream>>>(img, Dbuf);
  k_coldist<<<dim3(16, nch), dim3(256), 0, stream>>>(Dbuf);
  k_final<<<dim3(16, 16, nch), dim3(16, 16), 0, stream>>>(Dbuf, out);
}

// Round 4
// 61.519 us; speedup vs baseline: 3.1491x; 1.1373x over previous
//
#include <hip/hip_runtime.h>

// ConvDistanceTransform closed form:
//   D = Chebyshev distance transform of seeds (exact, separable)
//   i = (D-1)/3 ; out = 3.5*i - 0.35*log( sum_{q in 7x7, D(q)<=3i} exp(-|p-q|_2/0.35) )
// Kernel A: per-row 1-D distance d1 (wave-per-row register scans), padded layout.
// Kernel B (fused): per 32-col slab: stage d1 in LDS -> column min-max transform
//                   in LDS -> thresholded 7x7 log-sum-exp epilogue -> out.

#define BIGV (1 << 20)
#define STRIDE 288          // d1 row stride (bytes): 16-col guard each side
#define CHSZ (256 * STRIDE)
#define LW 80               // LDS row stride (bytes) for bank spread

// ---------- Kernel A: row distances ----------
__global__ __launch_bounds__(256) void k_rowdist(const float* __restrict__ img,
                                                 unsigned char* __restrict__ d1) {
  const int lane = threadIdx.x & 63;
  const int wv = threadIdx.x >> 6;
  const int row = blockIdx.x * 4 + wv;  // ch*256 + y
  const int x0 = lane * 4;

  const float4 v = *reinterpret_cast<const float4*>(&img[(size_t)row * 256 + x0]);

  int c0 = (v.x != 0.0f) ? -x0 : BIGV;
  int c1 = (v.y != 0.0f) ? -(x0 + 1) : BIGV;
  int c2 = (v.z != 0.0f) ? -(x0 + 2) : BIGV;
  int c3 = (v.w != 0.0f) ? -(x0 + 3) : BIGV;
  const int p0 = c0;
  const int p1 = min(c1, p0);
  const int p2 = min(c2, p1);
  const int p3 = min(c3, p2);
  int incl = p3;
#pragma unroll
  for (int off = 1; off < 64; off <<= 1) {
    int o = __shfl_up(incl, off, 64);
    if (lane >= off) incl = min(incl, o);
  }
  int excl = __shfl_up(incl, 1, 64);
  if (lane == 0) excl = BIGV;
  const int df0 = x0 + min(p0, excl);
  const int df1 = x0 + 1 + min(p1, excl);
  const int df2 = x0 + 2 + min(p2, excl);
  const int df3 = x0 + 3 + min(p3, excl);

  int g0 = (v.x != 0.0f) ? x0 : BIGV;
  int g1 = (v.y != 0.0f) ? (x0 + 1) : BIGV;
  int g2 = (v.z != 0.0f) ? (x0 + 2) : BIGV;
  int g3 = (v.w != 0.0f) ? (x0 + 3) : BIGV;
  const int q3 = g3;
  const int q2 = min(g2, q3);
  const int q1 = min(g1, q2);
  const int q0 = min(g0, q1);
  int incl2 = q0;
#pragma unroll
  for (int off = 1; off < 64; off <<= 1) {
    int o = __shfl_down(incl2, off, 64);
    if (lane < 64 - off) incl2 = min(incl2, o);
  }
  int excl2 = __shfl_down(incl2, 1, 64);
  if (lane == 63) excl2 = BIGV;
  const int db0 = min(q0, excl2) - x0;
  const int db1 = min(q1, excl2) - (x0 + 1);
  const int db2 = min(q2, excl2) - (x0 + 2);
  const int db3 = min(q3, excl2) - (x0 + 3);

  const unsigned int d0 = (unsigned int)min(min(df0, db0), 255);
  const unsigned int d1v = (unsigned int)min(min(df1, db1), 255);
  const unsigned int d2 = (unsigned int)min(min(df2, db2), 255);
  const unsigned int d3 = (unsigned int)min(min(df3, db3), 255);
  const int ch = row >> 8, y = row & 255;
  *reinterpret_cast<unsigned int*>(&d1[(size_t)ch * CHSZ + y * STRIDE + 16 + x0]) =
      d0 | (d1v << 8) | (d2 << 16) | (d3 << 24);
}

// tap class by dx^2+dy^2: {1,2,4,5,8,9,10,13,18} -> 0..8 ; center = -1 (skip)
__device__ __constant__ const signed char kCls[7][7] = {
    {8, 7, 6, 5, 6, 7, 8},
    {7, 4, 3, 2, 3, 4, 7},
    {6, 3, 1, 0, 1, 3, 6},
    {5, 2, 0, -1, 0, 2, 5},
    {6, 3, 1, 0, 1, 3, 6},
    {7, 4, 3, 2, 3, 4, 7},
    {8, 7, 6, 5, 6, 7, 8}};

// ---------- Kernel B: fused column transform + epilogue ----------
__global__ __launch_bounds__(512) void k_fused(const unsigned char* __restrict__ d1,
                                               float* __restrict__ out) {
  const int ch = blockIdx.y;
  const int xt = blockIdx.x;  // 0..7
  const int x0 = xt * 32;
  const int tid = threadIdx.x;
  const int lastxt = (int)gridDim.x - 1;

  __shared__ __align__(16) unsigned char s1[256][LW];  // cols 0..63 <-> img x0-16..x0+47
  __shared__ __align__(16) unsigned char Ds[262][LW];  // rows 0..261 <-> y -3..258

  const unsigned char* src = d1 + (size_t)ch * CHSZ;
#pragma unroll
  for (int it = 0; it < 2; ++it) {
    const int idx = it * 512 + tid;  // 0..1023
    const int y = idx >> 2, seg = idx & 3;
    *reinterpret_cast<uint4*>(&s1[y][seg * 16]) =
        *reinterpret_cast<const uint4*>(&src[y * STRIDE + x0 + seg * 16]);
  }
  // pad rows (y=-3..-1, 256..258) of Ds = 255
  if (tid < 96) {
    const int r = tid >> 4, c = tid & 15;
    const int row = (r < 3) ? r : r + 256;  // 0,1,2,259,260,261
    *reinterpret_cast<unsigned int*>(&Ds[row][c * 4]) = 0xFFFFFFFFu;
  }
  __syncthreads();
  // zero ghost d1 cols (outside image) so the k-loop terminates fast; their Ds
  // values are forced to 255 afterwards.
  if (xt == 0) {
    for (int i = tid; i < 1024; i += 512) {
      const int y = i >> 2, c = i & 3;
      *reinterpret_cast<unsigned int*>(&s1[y][c * 4]) = 0u;
    }
  } else if (xt == lastxt) {
    for (int i = tid; i < 1024; i += 512) {
      const int y = i >> 2, c = i & 3;
      *reinterpret_cast<unsigned int*>(&s1[y][48 + c * 4]) = 0u;
    }
  }
  __syncthreads();

  // column pass: D(y,x) = min_y' max(|y-y'|, d1(y',x)), groups of 4 cols,
  // early-exit at k >= running best max. cols 12..51 (need 13..50).
#pragma unroll
  for (int it = 0; it < 5; ++it) {
    const int idx = it * 512 + tid;  // 0..2559
    const int y = idx / 10;
    const int g = idx - y * 10 + 3;  // 3..12
    const unsigned int c = *reinterpret_cast<const unsigned int*>(&s1[y][g * 4]);
    int b0 = c & 255, b1 = (c >> 8) & 255, b2 = (c >> 16) & 255, b3 = c >> 24;
    int bm = max(max(b0, b1), max(b2, b3));
    for (int k = 1; k < bm; ++k) {
      const int yu = max(y - k, 0), yd = min(y + k, 255);  // clamped = overestimates
      const unsigned int u = *reinterpret_cast<const unsigned int*>(&s1[yu][g * 4]);
      const unsigned int w = *reinterpret_cast<const unsigned int*>(&s1[yd][g * 4]);
      b0 = min(b0, max(k, (int)(u & 255)));
      b1 = min(b1, max(k, (int)((u >> 8) & 255)));
      b2 = min(b2, max(k, (int)((u >> 16) & 255)));
      b3 = min(b3, max(k, (int)(u >> 24)));
      b0 = min(b0, max(k, (int)(w & 255)));
      b1 = min(b1, max(k, (int)((w >> 8) & 255)));
      b2 = min(b2, max(k, (int)((w >> 16) & 255)));
      b3 = min(b3, max(k, (int)(w >> 24)));
      bm = max(max(b0, b1), max(b2, b3));
    }
    *reinterpret_cast<unsigned int*>(&Ds[y + 3][g * 4]) =
        (unsigned int)b0 | ((unsigned int)b1 << 8) | ((unsigned int)b2 << 16) |
        ((unsigned int)b3 << 24);
  }
  __syncthreads();
  // ghost image cols in the epilogue window must read 255
  if (xt == 0) {
    for (int y = tid; y < 262; y += 512)
      *reinterpret_cast<unsigned int*>(&Ds[y][12]) = 0xFFFFFFFFu;
  } else if (xt == lastxt) {
    for (int y = tid; y < 262; y += 512)
      *reinterpret_cast<unsigned int*>(&Ds[y][48]) = 0xFFFFFFFFu;
  }
  __syncthreads();

  // epilogue: per px, 48 taps (center always excluded), per-class counts
  const float w0 = expf(-1.0f / 0.35f);
  const float w1 = expf(-1.41421356f / 0.35f);
  const float w2 = expf(-2.0f / 0.35f);
  const float w3 = expf(-2.23606798f / 0.35f);
  const float w4 = expf(-2.82842712f / 0.35f);
  const float w5 = expf(-3.0f / 0.35f);
  const float w6 = expf(-3.16227766f / 0.35f);
  const float w7 = expf(-3.60555128f / 0.35f);
  const float w8 = expf(-4.24264069f / 0.35f);

#pragma unroll 1
  for (int it = 0; it < 16; ++it) {
    const int idx = it * 512 + tid;  // 0..8191
    const int yy = idx >> 5, xl = idx & 31;
    const int D0 = Ds[yy + 3][16 + xl];
    const int im1 = max(D0 - 1, 0);
    const int i = (im1 * 21846) >> 16;  // floor(im1/3), exact for im1<=254
    const int T = 3 * i;

    const int cs = 13 + xl;        // window start col in LDS
    const int cb = cs & ~3;        // aligned dword base (cs-cb<=3, 7 bytes in 12)
    const int a = cs & 3;
    int cnt[9] = {0, 0, 0, 0, 0, 0, 0, 0, 0};
#pragma unroll
    for (int dy = 0; dy < 7; ++dy) {
      const unsigned char* rp = &Ds[yy + dy][cb];
      const unsigned int W0 = *reinterpret_cast<const unsigned int*>(rp);
      const unsigned int W1 = *reinterpret_cast<const unsigned int*>(rp + 4);
      const unsigned int W2 = *reinterpret_cast<const unsigned int*>(rp + 8);
      const unsigned int lo = __builtin_amdgcn_alignbyte(W1, W0, a);
      const unsigned int hi = __builtin_amdgcn_alignbyte(W2, W1, a);
#pragma unroll
      for (int dx = 0; dx < 7; ++dx) {
        const int cl = kCls[dy][dx];
        if (cl < 0) continue;  // center
        const unsigned int q =
            (dx < 4) ? ((lo >> (8 * dx)) & 255u) : ((hi >> (8 * (dx - 4))) & 255u);
        cnt[cl] += (q <= (unsigned int)T) ? 1 : 0;
      }
    }
    float conv = 0.0f;
    conv = fmaf((float)cnt[0], w0, conv);
    conv = fmaf((float)cnt[1], w1, conv);
    conv = fmaf((float)cnt[2], w2, conv);
    conv = fmaf((float)cnt[3], w3, conv);
    conv = fmaf((float)cnt[4], w4, conv);
    conv = fmaf((float)cnt[5], w5, conv);
    conv = fmaf((float)cnt[6], w6, conv);
    conv = fmaf((float)cnt[7], w7, conv);
    conv = fmaf((float)cnt[8], w8, conv);

    float res = 0.0f;
    if (D0 > 0 && conv > 0.0f) res = fmaf(3.5f, (float)i, -0.35f * __logf(conv));
    out[(size_t)ch * 65536 + (size_t)yy * 256 + x0 + xl] = res;
  }
}

extern "C" void kernel_launch(void* const* d_in, const int* in_sizes, int n_in,
                              void* d_out, int out_size, void* d_ws, size_t ws_size,
                              hipStream_t stream) {
  const float* img = (const float*)d_in[0];
  float* out = (float*)d_out;
  unsigned char* Dbuf = (unsigned char*)d_ws;

  const int total = in_sizes[0];  // B*C*H*W
  const int nch = total >> 16;    // B*C (H=W=256)

  k_rowdist<<<dim3(nch * 64), dim3(256), 0, stream>>>(img, Dbuf);
  k_fused<<<dim3(8, nch), dim3(512), 0, stream>>>(Dbuf, out);
}